// Round 10
// baseline (104.924 us; speedup 1.0000x reference)
//
#include <hip/hip_runtime.h>
#include <math.h>

// Problem constants (from reference)
constexpr int kB = 256, kT = 8, kS = 200, kR = 8, kD = 64, kF = 20;
constexpr int kSP = 224;                     // s padded to 7 K-tiles of 32
constexpr float kW1 = 3.14159265358979323846f / 19.0f;

typedef __attribute__((ext_vector_type(8))) short s16x8;   // 8 bf16 = 4 VGPR
typedef __attribute__((ext_vector_type(4))) float f32x4;

// split-bf16: x = hi + lo + eps, |eps| ~ 2^-16 |x| (validated R9: absmax 3.8e-6)
__device__ __forceinline__ unsigned short bf_hi(float x, float& hf) {
    unsigned u = __float_as_uint(x) & 0xffff0000u;
    hf = __uint_as_float(u);
    return (unsigned short)(u >> 16);
}
__device__ __forceinline__ unsigned short bf_rne(float x) {
    unsigned v = __float_as_uint(x);
    return (unsigned short)((v + 0x7fffu + ((v >> 16) & 1u)) >> 16);
}

// ---------------------------------------------------------------------------
// Kernel 1 (prep): one block per b. Fuses:
//  A) seq -> bf16 hi/lo split, written [B][S][D] (GEMM1 A-operand) and staged
//     in LDS ([200][66] pad: ushort2-aligned, transpose reads bank-stride 33
//     -> conflict-free),
//  B) decay[b][r][s] (R9-validated math: one __sincosf + angle recurrence),
//  C) transposed planes [B][D][224] (GEMM2 B-operand), s in [200,224) zeroed
//     so GEMM2's K-pad needs no in-kernel handling.
// Rationale: R9's main kernel spent its time splitting seq to bf16 (VALU on
// the critical path before each MFMA) and doing 56 scalar d-column loads per
// lane in GEMM2 -- both hoisted here, done ONCE per b instead of 8x.
// ---------------------------------------------------------------------------
__global__ __launch_bounds__(256) void prep_kernel(
    const float* __restrict__ seq,   // [B,S,D]
    const float* __restrict__ dt,    // [B,S]
    const float* __restrict__ fr,    // [R,F]
    const float* __restrict__ fi,    // [R,F]
    const int*   __restrict__ vm,    // [B,S]
    float* __restrict__ dec,                 // [B,R,S]
    unsigned short* __restrict__ seqH,       // [B,S,D]
    unsigned short* __restrict__ seqL,       // [B,S,D]
    unsigned short* __restrict__ seqTH,      // [B,D,224]
    unsigned short* __restrict__ seqTL)      // [B,D,224]
{
    __shared__ unsigned short lh[kS][66], ll[kS][66];   // 51.6 KB

    const int b = blockIdx.x, tid = threadIdx.x;

    // ---- Phase A: split + store [S][D] + LDS stage
    {
        const float4* sb = (const float4*)(seq + (size_t)b * kS * kD);
        unsigned short* gh = seqH + (size_t)b * kS * kD;
        unsigned short* gl = seqL + (size_t)b * kS * kD;
        for (int idx = tid; idx < kS * kD / 4; idx += 256) {   // 3200
            float4 x = sb[idx];
            const int s = idx >> 4, d0 = (idx & 15) * 4;
            ushort4 h, lo; float hf;
            h.x = bf_hi(x.x, hf); lo.x = bf_rne(x.x - hf);
            h.y = bf_hi(x.y, hf); lo.y = bf_rne(x.y - hf);
            h.z = bf_hi(x.z, hf); lo.z = bf_rne(x.z - hf);
            h.w = bf_hi(x.w, hf); lo.w = bf_rne(x.w - hf);
            *(ushort4*)&gh[idx * 4] = h;
            *(ushort4*)&gl[idx * 4] = lo;
            *(ushort2*)&lh[s][d0]     = make_ushort2(h.x, h.y);
            *(ushort2*)&lh[s][d0 + 2] = make_ushort2(h.z, h.w);
            *(ushort2*)&ll[s][d0]     = make_ushort2(lo.x, lo.y);
            *(ushort2*)&ll[s][d0 + 2] = make_ushort2(lo.z, lo.w);
        }
    }

    // ---- Phase B: decay (no LDS dependency; overlaps with A's stores)
    {
        const int r = tid >> 5, j = tid & 31;
        float frr[kF], fir[kF];
        const float4* f4 = (const float4*)(fr + r * kF);
        const float4* g4 = (const float4*)(fi + r * kF);
#pragma unroll
        for (int c = 0; c < 5; ++c) {
            float4 a = f4[c], g = g4[c];
            frr[4*c+0]=a.x; frr[4*c+1]=a.y; frr[4*c+2]=a.z; frr[4*c+3]=a.w;
            fir[4*c+0]=g.x; fir[4*c+1]=g.y; fir[4*c+2]=g.z; fir[4*c+3]=g.w;
        }
#pragma unroll
        for (int it = 0; it < 7; ++it) {
            const int s = j + 32 * it;
            if (s < kS) {
                const float tt = dt[b * kS + s];
                const bool valid = vm[b * kS + s] != 0;
                float s1, c1;
                __sincosf(kW1 * tt, &s1, &c1);
                float ck = c1, sk = s1;
                float acc = frr[0] + c1 * frr[1] - s1 * fir[1];
#pragma unroll
                for (int k = 2; k < kF; ++k) {
                    float cn = ck * c1 - sk * s1;
                    float sn = sk * c1 + ck * s1;
                    ck = cn; sk = sn;
                    acc += ck * frr[k] - sk * fir[k];
                }
                float v = fminf(fmaxf(acc * (1.0f / (2.0f * kF)), 0.f), 1.f);
                dec[(b * kR + r) * kS + s] = valid ? v : 0.f;
            }
        }
    }
    __syncthreads();

    // ---- Phase C: transpose from LDS, zero-pad s in [200,224)
    {
        unsigned short* th = seqTH + (size_t)b * kD * kSP;
        unsigned short* tl = seqTL + (size_t)b * kD * kSP;
        for (int idx = tid; idx < kD * kSP; idx += 256) {   // 14336
            const int d = idx / kSP, s = idx - d * kSP;
            th[idx] = (s < kS) ? lh[s][d] : (unsigned short)0;
            tl[idx] = (s < kS) ? ll[s][d] : (unsigned short)0;
        }
    }
}

// ---------------------------------------------------------------------------
// Kernel 2: MFMA main (R9 structure, validated fragment maps; operands now
// pre-split in global -> pure load+MFMA phases). One block per (b, t-pair),
// grid 1024, 256 threads = 4 waves. n = t_local*8 + r in [0,16).
//   P0    : riB[n][d] = (rel+tv)*target -> LDS bf16 hi/lo (only split left)
//   GEMM1 : att_raw[n][s]; A = seqH/L (16B loads), B = riB; 3-MFMA split.
//   P2    : masked softmax over s (wave w: rows 4w..4w+3) * dec -> ath/atl.
//   GEMM2 : out[n][d]; A = ath/atl (LDS), B = seqTH/L (16B loads, K=224).
// Plain __launch_bounds__ (R5/R6: min-waves arg pins VGPR -> spills).
// ---------------------------------------------------------------------------
__global__ __launch_bounds__(256) void rda_mfma(
    const float* __restrict__ target, // [B,T,D]
    const float* __restrict__ tv,     // [B,T,R,D]
    const int*   __restrict__ vm,     // [B,S]
    const float* __restrict__ rel,    // [R,D]
    const float* __restrict__ dec,    // [B,R,S]
    const unsigned short* __restrict__ seqH,   // [B,S,D]
    const unsigned short* __restrict__ seqL,   // [B,S,D]
    const unsigned short* __restrict__ seqTH,  // [B,D,224]
    const unsigned short* __restrict__ seqTL,  // [B,D,224]
    float* __restrict__ out)          // [B,T,R,D]
{
    __shared__ unsigned short riBh[16][72], riBl[16][72];  // 4.5 KB
    __shared__ float attr[16][212];                        // 13.25 KB
    __shared__ unsigned short ath[16][232], atl[16][232];  // 14.5 KB

    const int o = blockIdx.x, b = o & 255, g = o >> 8, t0 = 2 * g;
    const int tid = threadIdx.x, w = tid >> 6, l = tid & 63;
    const int lm = l & 15, lq = l >> 4;

    // ---- P0: riB
    {
        const int n = tid >> 4, d0 = (tid & 15) * 4;
        const int tl_ = n >> 3, r = n & 7;
        const int btl = b * kT + t0 + tl_;
        float4 rv  = *(const float4*)(rel + r * kD + d0);
        float4 tvv = *(const float4*)(tv + ((size_t)btl * kR + r) * kD + d0);
        float4 tg  = *(const float4*)(target + (size_t)btl * kD + d0);
        float x[4] = {(rv.x+tvv.x)*tg.x, (rv.y+tvv.y)*tg.y,
                      (rv.z+tvv.z)*tg.z, (rv.w+tvv.w)*tg.w};
        ushort4 h, lo; float hf;
        h.x = bf_hi(x[0], hf); lo.x = bf_rne(x[0] - hf);
        h.y = bf_hi(x[1], hf); lo.y = bf_rne(x[1] - hf);
        h.z = bf_hi(x[2], hf); lo.z = bf_rne(x[2] - hf);
        h.w = bf_hi(x[3], hf); lo.w = bf_rne(x[3] - hf);
        *(ushort4*)&riBh[n][d0] = h;
        *(ushort4*)&riBl[n][d0] = lo;
    }
    __syncthreads();

    // ---- GEMM1: scores (D: col n=lm, row s=Mt*16+lq*4+i -- R9-validated)
    for (int Mt = w; Mt < 13; Mt += 4) {
        const int srow = min(Mt * 16 + lm, kS - 1);   // clamped pad rows unused
        const unsigned short* ph = seqH + ((size_t)b * kS + srow) * kD;
        const unsigned short* pl = seqL + ((size_t)b * kS + srow) * kD;
        f32x4 acc = {0.f, 0.f, 0.f, 0.f};
#pragma unroll
        for (int Kt = 0; Kt < 2; ++Kt) {
            const int d0 = Kt * 32 + lq * 8;
            s16x8 ah = *(const s16x8*)&ph[d0];
            s16x8 al = *(const s16x8*)&pl[d0];
            s16x8 bh = *(const s16x8*)&riBh[lm][d0];
            s16x8 bl = *(const s16x8*)&riBl[lm][d0];
            acc = __builtin_amdgcn_mfma_f32_16x16x32_bf16(ah, bh, acc, 0, 0, 0);
            acc = __builtin_amdgcn_mfma_f32_16x16x32_bf16(ah, bl, acc, 0, 0, 0);
            acc = __builtin_amdgcn_mfma_f32_16x16x32_bf16(al, bh, acc, 0, 0, 0);
        }
        *(f32x4*)&attr[lm][Mt * 16 + lq * 4] = acc;
    }
    __syncthreads();

    // ---- P2: masked softmax * dec, rows n = 4w..4w+3 -> bf16 hi/lo
    {
        bool ok0 = vm[b * kS + l] != 0;
        bool ok1 = vm[b * kS + l + 64] != 0;
        bool ok2 = vm[b * kS + l + 128] != 0;
        bool ok3 = (l < 8) && (vm[b * kS + 192 + l] != 0);
        const int s3 = (l < 8) ? 192 + l : kS - 1;
#pragma unroll
        for (int j = 0; j < 4; ++j) {
            const int n = 4 * w + j, r = n & 7;
            float a0 = ok0 ? attr[n][l]       : -INFINITY;
            float a1 = ok1 ? attr[n][l + 64]  : -INFINITY;
            float a2 = ok2 ? attr[n][l + 128] : -INFINITY;
            float a3 = ok3 ? attr[n][s3]      : -INFINITY;
            float m = fmaxf(fmaxf(a0, a1), fmaxf(a2, a3));
#pragma unroll
            for (int off = 32; off; off >>= 1) m = fmaxf(m, __shfl_xor(m, off));
            float e0 = __expf(a0 - m), e1 = __expf(a1 - m);
            float e2 = __expf(a2 - m), e3 = ok3 ? __expf(a3 - m) : 0.f;
            float ssum = e0 + e1 + e2 + e3;
#pragma unroll
            for (int off = 32; off; off >>= 1) ssum += __shfl_xor(ssum, off);
            const float inv = 1.0f / ssum;
            const float* dg = dec + ((size_t)b * kR + r) * kS;
            float p0 = e0 * inv * dg[l];
            float p1 = e1 * inv * dg[l + 64];
            float p2 = e2 * inv * dg[l + 128];
            float p3 = ok3 ? e3 * inv * dg[192 + l] : 0.f;
            float hf;
            ath[n][l]       = bf_hi(p0, hf); atl[n][l]       = bf_rne(p0 - hf);
            ath[n][l + 64]  = bf_hi(p1, hf); atl[n][l + 64]  = bf_rne(p1 - hf);
            ath[n][l + 128] = bf_hi(p2, hf); atl[n][l + 128] = bf_rne(p2 - hf);
            if (l < 32) {   // s in [192,224): real for l<8, ZERO K-pad else
                float pv = (l < 8) ? p3 : 0.f;
                ath[n][192 + l] = bf_hi(pv, hf); atl[n][192 + l] = bf_rne(pv - hf);
            }
        }
    }
    __syncthreads();

    // ---- GEMM2: context; wave w owns d-cols [16w,16w+16); K=224 via seqT
    {
        const int dcol = w * 16 + lm;
        const unsigned short* th = seqTH + ((size_t)b * kD + dcol) * kSP;
        const unsigned short* tl_ = seqTL + ((size_t)b * kD + dcol) * kSP;
        f32x4 acc = {0.f, 0.f, 0.f, 0.f};
#pragma unroll
        for (int Kt = 0; Kt < 7; ++Kt) {
            const int s0 = Kt * 32 + lq * 8;
            s16x8 bh  = *(const s16x8*)&th[s0];
            s16x8 bl  = *(const s16x8*)&tl_[s0];
            s16x8 ahh = *(const s16x8*)&ath[lm][s0];
            s16x8 alo = *(const s16x8*)&atl[lm][s0];
            acc = __builtin_amdgcn_mfma_f32_16x16x32_bf16(ahh, bh, acc, 0, 0, 0);
            acc = __builtin_amdgcn_mfma_f32_16x16x32_bf16(ahh, bl, acc, 0, 0, 0);
            acc = __builtin_amdgcn_mfma_f32_16x16x32_bf16(alo, bh, acc, 0, 0, 0);
        }
#pragma unroll
        for (int i = 0; i < 4; ++i) {
            const int n = lq * 4 + i, tl2 = n >> 3, r = n & 7;
            out[(((size_t)(b * kT + t0 + tl2)) * kR + r) * kD + dcol] = acc[i];
        }
    }
}

extern "C" void kernel_launch(void* const* d_in, const int* in_sizes, int n_in,
                              void* d_out, int out_size, void* d_ws, size_t ws_size,
                              hipStream_t stream) {
    const float* seq    = (const float*)d_in[0];
    const float* dt     = (const float*)d_in[1];
    const float* target = (const float*)d_in[2];
    const float* tv     = (const float*)d_in[3];
    const int*   vm     = (const int*)  d_in[4];
    const float* rel    = (const float*)d_in[5];
    const float* fr     = (const float*)d_in[6];
    const float* fi     = (const float*)d_in[7];
    float* out = (float*)d_out;

    // d_ws layout (29.4 MB total; ws is poison-filled by harness regardless):
    float* dec = (float*)d_ws;                                   // 1.6 MB
    unsigned short* seqH  = (unsigned short*)((char*)d_ws + 1638400);
    unsigned short* seqL  = seqH + (size_t)kB * kS * kD;         // +6.55 MB
    unsigned short* seqTH = seqL + (size_t)kB * kS * kD;         // +6.55 MB
    unsigned short* seqTL = seqTH + (size_t)kB * kD * kSP;       // +7.34 MB

    prep_kernel<<<kB, 256, 0, stream>>>(seq, dt, fr, fi, vm,
                                        dec, seqH, seqL, seqTH, seqTL);
    rda_mfma<<<kB * 4, 256, 0, stream>>>(target, tv, vm, rel, dec,
                                         seqH, seqL, seqTH, seqTL, out);
}

// Round 11
// 98.764 us; speedup vs baseline: 1.0624x; 1.0624x over previous
//
#include <hip/hip_runtime.h>
#include <math.h>

// Problem constants (from reference)
constexpr int kB = 256, kT = 8, kS = 200, kR = 8, kD = 64, kF = 20;
constexpr int kSP = 224;                     // s padded to 7 K-tiles of 32
constexpr float kW1 = 3.14159265358979323846f / 19.0f;

typedef __attribute__((ext_vector_type(8))) short s16x8;   // 8 bf16 = 4 VGPR
typedef __attribute__((ext_vector_type(4))) float f32x4;

// split-bf16: x = hi + lo + eps, |eps| ~ 2^-16 |x| (validated R9/R10: 3.8e-6)
__device__ __forceinline__ unsigned short bf_hi(float x, float& hf) {
    unsigned u = __float_as_uint(x) & 0xffff0000u;
    hf = __uint_as_float(u);
    return (unsigned short)(u >> 16);
}
__device__ __forceinline__ unsigned short bf_rne(float x) {
    unsigned v = __float_as_uint(x);
    return (unsigned short)((v + 0x7fffu + ((v >> 16) & 1u)) >> 16);
}

// ---------------------------------------------------------------------------
// Kernel 1 (prep, R11 rebuild): grid 7*256 = 1792, one block per (b, 32-row
// s-slice). R10's prep was 1 block/CU (grid 256) + 51.6 KB LDS -> ~1 wave/SIMD
// latency disaster. This version: 8.5 KB LDS, 7 blocks/CU avg, all I/O
// coalesced, decay fused per-slice (thread = r*32+s_local = 256 exactly).
//   A) read 32 seq rows, split bf16 hi/lo -> seqH/L [B][S][D] + LDS stage
//      ([32][66] pad: transpose reads hit stride-33 banks, conflict-free)
//   B) decay for this slice's s (one __sincosf + 20-term angle recurrence)
//   C) transpose-write seqTH/TL [B][D][224]; s in [200,224) zeroed (K-pad)
// ---------------------------------------------------------------------------
__global__ __launch_bounds__(256) void prep_kernel(
    const float* __restrict__ seq,   // [B,S,D]
    const float* __restrict__ dt,    // [B,S]
    const float* __restrict__ fr,    // [R,F]
    const float* __restrict__ fi,    // [R,F]
    const int*   __restrict__ vm,    // [B,S]
    float* __restrict__ dec,                 // [B,R,S]
    unsigned short* __restrict__ seqH,       // [B,S,D]
    unsigned short* __restrict__ seqL,       // [B,S,D]
    unsigned short* __restrict__ seqTH,      // [B,D,224]
    unsigned short* __restrict__ seqTL)      // [B,D,224]
{
    __shared__ unsigned short lh[32][66], ll[32][66];   // 8.45 KB

    const int o = blockIdx.x, b = o & 255, slice = o >> 8;
    const int s0 = slice * 32;
    const int tid = threadIdx.x;

    // ---- Phase A: split + store [S][D] + LDS stage (2 iters of 256)
    {
        unsigned short* gh = seqH + (size_t)b * kS * kD;
        unsigned short* gl = seqL + (size_t)b * kS * kD;
#pragma unroll
        for (int it = 0; it < 2; ++it) {
            const int idx = tid + it * 256;            // [0,512)
            const int sl = idx >> 4, d0 = (idx & 15) * 4;
            const int s = s0 + sl;
            float4 x = make_float4(0.f, 0.f, 0.f, 0.f);
            if (s < kS)
                x = *(const float4*)(seq + ((size_t)b * kS + s) * kD + d0);
            ushort4 h, lo; float hf;
            h.x = bf_hi(x.x, hf); lo.x = bf_rne(x.x - hf);
            h.y = bf_hi(x.y, hf); lo.y = bf_rne(x.y - hf);
            h.z = bf_hi(x.z, hf); lo.z = bf_rne(x.z - hf);
            h.w = bf_hi(x.w, hf); lo.w = bf_rne(x.w - hf);
            if (s < kS) {
                *(ushort4*)&gh[s * kD + d0] = h;
                *(ushort4*)&gl[s * kD + d0] = lo;
            }
            *(ushort2*)&lh[sl][d0]     = make_ushort2(h.x, h.y);
            *(ushort2*)&lh[sl][d0 + 2] = make_ushort2(h.z, h.w);
            *(ushort2*)&ll[sl][d0]     = make_ushort2(lo.x, lo.y);
            *(ushort2*)&ll[sl][d0 + 2] = make_ushort2(lo.z, lo.w);
        }
    }

    // ---- Phase B: decay for this slice (thread = r*32 + s_local)
    {
        const int r = tid >> 5, sl = tid & 31;
        const int s = s0 + sl;
        if (s < kS) {
            float frr[kF], fir[kF];
            const float4* f4 = (const float4*)(fr + r * kF);
            const float4* g4 = (const float4*)(fi + r * kF);
#pragma unroll
            for (int c = 0; c < 5; ++c) {
                float4 a = f4[c], g = g4[c];
                frr[4*c+0]=a.x; frr[4*c+1]=a.y; frr[4*c+2]=a.z; frr[4*c+3]=a.w;
                fir[4*c+0]=g.x; fir[4*c+1]=g.y; fir[4*c+2]=g.z; fir[4*c+3]=g.w;
            }
            const float tt = dt[b * kS + s];
            const bool valid = vm[b * kS + s] != 0;
            float s1, c1;
            __sincosf(kW1 * tt, &s1, &c1);
            float ck = c1, sk = s1;
            float acc = frr[0] + c1 * frr[1] - s1 * fir[1];
#pragma unroll
            for (int k = 2; k < kF; ++k) {
                float cn = ck * c1 - sk * s1;
                float sn = sk * c1 + ck * s1;
                ck = cn; sk = sn;
                acc += ck * frr[k] - sk * fir[k];
            }
            float v = fminf(fmaxf(acc * (1.0f / (2.0f * kF)), 0.f), 1.f);
            dec[(b * kR + r) * kS + s] = valid ? v : 0.f;
        }
    }
    __syncthreads();

    // ---- Phase C: transpose-write seqT planes (8 iters of 256)
    {
        unsigned short* th = seqTH + (size_t)b * kD * kSP + s0;
        unsigned short* tl = seqTL + (size_t)b * kD * kSP + s0;
#pragma unroll
        for (int it = 0; it < 8; ++it) {
            const int idx = tid + it * 256;            // [0,2048)
            const int d = idx >> 5, sl = idx & 31;
            th[(size_t)d * kSP + sl] = lh[sl][d];      // LDS stride 33 banks: ok
            tl[(size_t)d * kSP + sl] = ll[sl][d];
        }
    }
}

// ---------------------------------------------------------------------------
// Kernel 2: MFMA main — VERBATIM from R10 (validated, absmax 3.8e-6).
// One block per (b, t-pair), grid 1024, 256 threads = 4 waves.
// ---------------------------------------------------------------------------
__global__ __launch_bounds__(256) void rda_mfma(
    const float* __restrict__ target, // [B,T,D]
    const float* __restrict__ tv,     // [B,T,R,D]
    const int*   __restrict__ vm,     // [B,S]
    const float* __restrict__ rel,    // [R,D]
    const float* __restrict__ dec,    // [B,R,S]
    const unsigned short* __restrict__ seqH,   // [B,S,D]
    const unsigned short* __restrict__ seqL,   // [B,S,D]
    const unsigned short* __restrict__ seqTH,  // [B,D,224]
    const unsigned short* __restrict__ seqTL,  // [B,D,224]
    float* __restrict__ out)          // [B,T,R,D]
{
    __shared__ unsigned short riBh[16][72], riBl[16][72];  // 4.5 KB
    __shared__ float attr[16][212];                        // 13.25 KB
    __shared__ unsigned short ath[16][232], atl[16][232];  // 14.5 KB

    const int o = blockIdx.x, b = o & 255, g = o >> 8, t0 = 2 * g;
    const int tid = threadIdx.x, w = tid >> 6, l = tid & 63;
    const int lm = l & 15, lq = l >> 4;

    // ---- P0: riB
    {
        const int n = tid >> 4, d0 = (tid & 15) * 4;
        const int tl_ = n >> 3, r = n & 7;
        const int btl = b * kT + t0 + tl_;
        float4 rv  = *(const float4*)(rel + r * kD + d0);
        float4 tvv = *(const float4*)(tv + ((size_t)btl * kR + r) * kD + d0);
        float4 tg  = *(const float4*)(target + (size_t)btl * kD + d0);
        float x[4] = {(rv.x+tvv.x)*tg.x, (rv.y+tvv.y)*tg.y,
                      (rv.z+tvv.z)*tg.z, (rv.w+tvv.w)*tg.w};
        ushort4 h, lo; float hf;
        h.x = bf_hi(x[0], hf); lo.x = bf_rne(x[0] - hf);
        h.y = bf_hi(x[1], hf); lo.y = bf_rne(x[1] - hf);
        h.z = bf_hi(x[2], hf); lo.z = bf_rne(x[2] - hf);
        h.w = bf_hi(x[3], hf); lo.w = bf_rne(x[3] - hf);
        *(ushort4*)&riBh[n][d0] = h;
        *(ushort4*)&riBl[n][d0] = lo;
    }
    __syncthreads();

    // ---- GEMM1: scores (D: col n=lm, row s=Mt*16+lq*4+i — R9-validated)
    for (int Mt = w; Mt < 13; Mt += 4) {
        const int srow = min(Mt * 16 + lm, kS - 1);   // clamped pad rows unused
        const unsigned short* ph = seqH + ((size_t)b * kS + srow) * kD;
        const unsigned short* pl = seqL + ((size_t)b * kS + srow) * kD;
        f32x4 acc = {0.f, 0.f, 0.f, 0.f};
#pragma unroll
        for (int Kt = 0; Kt < 2; ++Kt) {
            const int d0 = Kt * 32 + lq * 8;
            s16x8 ah = *(const s16x8*)&ph[d0];
            s16x8 al = *(const s16x8*)&pl[d0];
            s16x8 bh = *(const s16x8*)&riBh[lm][d0];
            s16x8 bl = *(const s16x8*)&riBl[lm][d0];
            acc = __builtin_amdgcn_mfma_f32_16x16x32_bf16(ah, bh, acc, 0, 0, 0);
            acc = __builtin_amdgcn_mfma_f32_16x16x32_bf16(ah, bl, acc, 0, 0, 0);
            acc = __builtin_amdgcn_mfma_f32_16x16x32_bf16(al, bh, acc, 0, 0, 0);
        }
        *(f32x4*)&attr[lm][Mt * 16 + lq * 4] = acc;
    }
    __syncthreads();

    // ---- P2: masked softmax * dec, rows n = 4w..4w+3 -> bf16 hi/lo
    {
        bool ok0 = vm[b * kS + l] != 0;
        bool ok1 = vm[b * kS + l + 64] != 0;
        bool ok2 = vm[b * kS + l + 128] != 0;
        bool ok3 = (l < 8) && (vm[b * kS + 192 + l] != 0);
        const int s3 = (l < 8) ? 192 + l : kS - 1;
#pragma unroll
        for (int j = 0; j < 4; ++j) {
            const int n = 4 * w + j, r = n & 7;
            float a0 = ok0 ? attr[n][l]       : -INFINITY;
            float a1 = ok1 ? attr[n][l + 64]  : -INFINITY;
            float a2 = ok2 ? attr[n][l + 128] : -INFINITY;
            float a3 = ok3 ? attr[n][s3]      : -INFINITY;
            float m = fmaxf(fmaxf(a0, a1), fmaxf(a2, a3));
#pragma unroll
            for (int off = 32; off; off >>= 1) m = fmaxf(m, __shfl_xor(m, off));
            float e0 = __expf(a0 - m), e1 = __expf(a1 - m);
            float e2 = __expf(a2 - m), e3 = ok3 ? __expf(a3 - m) : 0.f;
            float ssum = e0 + e1 + e2 + e3;
#pragma unroll
            for (int off = 32; off; off >>= 1) ssum += __shfl_xor(ssum, off);
            const float inv = 1.0f / ssum;
            const float* dg = dec + ((size_t)b * kR + r) * kS;
            float p0 = e0 * inv * dg[l];
            float p1 = e1 * inv * dg[l + 64];
            float p2 = e2 * inv * dg[l + 128];
            float p3 = ok3 ? e3 * inv * dg[192 + l] : 0.f;
            float hf;
            ath[n][l]       = bf_hi(p0, hf); atl[n][l]       = bf_rne(p0 - hf);
            ath[n][l + 64]  = bf_hi(p1, hf); atl[n][l + 64]  = bf_rne(p1 - hf);
            ath[n][l + 128] = bf_hi(p2, hf); atl[n][l + 128] = bf_rne(p2 - hf);
            if (l < 32) {   // s in [192,224): real for l<8, ZERO K-pad else
                float pv = (l < 8) ? p3 : 0.f;
                ath[n][192 + l] = bf_hi(pv, hf); atl[n][192 + l] = bf_rne(pv - hf);
            }
        }
    }
    __syncthreads();

    // ---- GEMM2: context; wave w owns d-cols [16w,16w+16); K=224 via seqT
    {
        const int dcol = w * 16 + lm;
        const unsigned short* th = seqTH + ((size_t)b * kD + dcol) * kSP;
        const unsigned short* tl_ = seqTL + ((size_t)b * kD + dcol) * kSP;
        f32x4 acc = {0.f, 0.f, 0.f, 0.f};
#pragma unroll
        for (int Kt = 0; Kt < 7; ++Kt) {
            const int s0 = Kt * 32 + lq * 8;
            s16x8 bh  = *(const s16x8*)&th[s0];
            s16x8 bl  = *(const s16x8*)&tl_[s0];
            s16x8 ahh = *(const s16x8*)&ath[lm][s0];
            s16x8 alo = *(const s16x8*)&atl[lm][s0];
            acc = __builtin_amdgcn_mfma_f32_16x16x32_bf16(ahh, bh, acc, 0, 0, 0);
            acc = __builtin_amdgcn_mfma_f32_16x16x32_bf16(ahh, bl, acc, 0, 0, 0);
            acc = __builtin_amdgcn_mfma_f32_16x16x32_bf16(alo, bh, acc, 0, 0, 0);
        }
#pragma unroll
        for (int i = 0; i < 4; ++i) {
            const int n = lq * 4 + i, tl2 = n >> 3, r = n & 7;
            out[(((size_t)(b * kT + t0 + tl2)) * kR + r) * kD + dcol] = acc[i];
        }
    }
}

extern "C" void kernel_launch(void* const* d_in, const int* in_sizes, int n_in,
                              void* d_out, int out_size, void* d_ws, size_t ws_size,
                              hipStream_t stream) {
    const float* seq    = (const float*)d_in[0];
    const float* dt     = (const float*)d_in[1];
    const float* target = (const float*)d_in[2];
    const float* tv     = (const float*)d_in[3];
    const int*   vm     = (const int*)  d_in[4];
    const float* rel    = (const float*)d_in[5];
    const float* fr     = (const float*)d_in[6];
    const float* fi     = (const float*)d_in[7];
    float* out = (float*)d_out;

    // d_ws layout (~29.4 MB; ws is poison-filled by harness regardless):
    float* dec = (float*)d_ws;                                   // 1.6 MB
    unsigned short* seqH  = (unsigned short*)((char*)d_ws + 1638400);
    unsigned short* seqL  = seqH + (size_t)kB * kS * kD;         // +6.55 MB
    unsigned short* seqTH = seqL + (size_t)kB * kS * kD;         // +6.55 MB
    unsigned short* seqTL = seqTH + (size_t)kB * kD * kSP;       // +7.34 MB

    prep_kernel<<<7 * kB, 256, 0, stream>>>(seq, dt, fr, fi, vm,
                                            dec, seqH, seqL, seqTH, seqTL);
    rda_mfma<<<kB * 4, 256, 0, stream>>>(target, tv, vm, rel, dec,
                                         seqH, seqL, seqTH, seqTL, out);
}